// Round 4
// baseline (220.985 us; speedup 1.0000x reference)
//
#include <hip/hip_runtime.h>

// GlobalAttentionPooling: tensor_square_0e -> selu -> @W -> segment softmax -> weighted segment sum
// N nodes, 80 f32 ft (32 scalar + 16 x 3-vec), NG=1024 graphs (sorted batch_index), F=664.
//
// Identities (validated rounds 1-3, absmax 3.9e-3):
//   selu const term cancels in softmax; pre-scale s by sqrt(log2e), v by sqrt(log2e/sqrt3)
//   so pair products are f*log2e -> exp2 directly. out_g = (sum nf*ex)/z_g.
//
// Round-4: pass1 code-size fix. Rounds 1-3 fully unrolled the 664-pair body (~35-40 KB of
// straight-line code > 32 KB I$) -> front-end-fetch bound (VALUBusy pinned at 41% across
// 3 structurally different kernels; occupancy increases didn't help). v4 rolls the loops:
//   - rows in LDS, SoA layout lds[c*256+lane] (conflict-free runtime-indexed reads)
//   - W pre-padded into f2 rows (zero for j<i slot) by the prep kernel -> uniform s_load
//   - unroll(disable) outer / unroll 2 inner -> ~2 KB body, I$-resident

typedef float f2 __attribute__((ext_vector_type(2)));

#define C0 32
#define C1 16
#define NODE_F 80
#define NG_CONST 1024

#define SELU_SCALE 1.0507009873554804934193349852946
#define SELU_ALPHA 1.6732632423543772848170429916717
#define LOG2E      1.4426950408889634073599246810019

#define CS_SCALE 1.2011224087864498f    // sqrt(log2e)
#define CV_SCALE 0.91271231102878545f   // sqrt(log2e/sqrt(3))

// triu flat index (j >= i): KS = i*32 - i(i-1)/2 + (j-i); KV adds 528 base
__device__ __forceinline__ int ks_idx(int i, int j) { return i * C0 - (i * (i - 1)) / 2 + (j - i); }
__device__ __forceinline__ int kv_idx(int i, int j) { return 528 + i * C1 - (i * (i - 1)) / 2 + (j - i); }

// ws float layout:
//   [0, 1024)          Ws  : 32 rows x 16 f2 (padded scalar-part W)
//   [1024, 1280)       Wv  : 16 rows x 8 f2  (padded vector-part W)
//   [1280, 1280+N)     ex
//   [1280+N, +NG+1)    bounds (int)
#define WS_OFF_WS 0
#define WS_OFF_WV 1024
#define WS_OFF_EX 1280

__global__ __launch_bounds__(256) void prep_kernel(
    const int* __restrict__ bi, const float* __restrict__ W,
    float* __restrict__ ws, int* __restrict__ bounds, int N)
{
    const int t = blockIdx.x * blockDim.x + threadIdx.x;
    if (t <= NG_CONST) {                       // segment bounds via binary search
        int lo = 0, hi = N;
        while (lo < hi) {
            int mid = (lo + hi) >> 1;
            if (bi[mid] < t) lo = mid + 1; else hi = mid;
        }
        bounds[t] = lo;
    } else if (t < 1025 + 512) {               // Ws: i in [0,32), q in [0,16)
        int u = t - 1025;
        int i = u >> 4, q = u & 15;
        int j0 = 2 * q, j1 = 2 * q + 1;
        float x = (j0 >= i) ? W[ks_idx(i, j0)] : 0.0f;
        float y = (j1 >= i) ? W[ks_idx(i, j1)] : 0.0f;
        ws[WS_OFF_WS + 2 * u]     = x;
        ws[WS_OFF_WS + 2 * u + 1] = y;
    } else if (t < 1025 + 512 + 128) {         // Wv: i in [0,16), q in [0,8)
        int u = t - 1537;
        int i = u >> 3, q = u & 7;
        int j0 = 2 * q, j1 = 2 * q + 1;
        float x = (j0 >= i) ? W[kv_idx(i, j0)] : 0.0f;
        float y = (j1 >= i) ? W[kv_idx(i, j1)] : 0.0f;
        ws[WS_OFF_WV + 2 * u]     = x;
        ws[WS_OFF_WV + 2 * u + 1] = y;
    }
}

__global__ __launch_bounds__(256, 3) void pass1_logits(
    const float* __restrict__ nf, const float* __restrict__ ws,
    float* __restrict__ ex_out, int N)
{
    __shared__ float lds[48 * 256];            // 48 KB; S phase uses rows 0..31, V rows 0..47
    const int tid  = threadIdx.x;
    const int base = blockIdx.x * 256;
    const float4* g4 = (const float4*)nf;
    const f2* Ws = (const f2*)(ws + WS_OFF_WS);
    const f2* Wv = (const f2*)(ws + WS_OFF_WV);

    // ---- stage S columns (0..31), SoA, pre-scaled ----
    #pragma unroll
    for (int it = 0; it < 8; ++it) {
        int idx = it * 256 + tid;
        int r = idx >> 3, c4 = idx & 7;
        int row = base + r; if (row > N - 1) row = N - 1;
        float4 v = g4[(size_t)row * 20 + c4];
        lds[(4 * c4 + 0) * 256 + r] = v.x * CS_SCALE;
        lds[(4 * c4 + 1) * 256 + r] = v.y * CS_SCALE;
        lds[(4 * c4 + 2) * 256 + r] = v.z * CS_SCALE;
        lds[(4 * c4 + 3) * 256 + r] = v.w * CS_SCALE;
    }
    __syncthreads();

    f2 accA = (f2)0.f, accB = (f2)0.f;

    // ---- scalar part: 528 triu pairs, rolled ----
    #pragma clang loop unroll(disable)
    for (int i = 0; i < C0; ++i) {
        const float si = lds[i * 256 + tid];
        const f2* wrow = Ws + i * 16;
        #pragma unroll 2
        for (int q = i >> 1; q < 16; ++q) {
            f2 sj = f2{lds[(2 * q) * 256 + tid], lds[(2 * q + 1) * 256 + tid]};
            f2 f = sj * f2{si, si};
            f2 p = __builtin_elementwise_max(f, (f2)0.f);
            f2 m = __builtin_elementwise_min(f, (f2)0.f);
            f2 e; e.x = __builtin_amdgcn_exp2f(m.x);
                  e.y = __builtin_amdgcn_exp2f(m.y);
            f2 w = wrow[q];                     // uniform address -> s_load
            accA = __builtin_elementwise_fma(w, p, accA);
            accB = __builtin_elementwise_fma(w, e, accB);
        }
    }
    __syncthreads();                            // all reads of S done before overwrite

    // ---- stage V columns (32..79 -> lds rows 0..47), SoA, pre-scaled ----
    #pragma unroll
    for (int it = 0; it < 12; ++it) {
        int idx = it * 256 + tid;
        int r = idx / 12, c4 = idx % 12;
        int row = base + r; if (row > N - 1) row = N - 1;
        float4 v = g4[(size_t)row * 20 + 8 + c4];
        lds[(4 * c4 + 0) * 256 + r] = v.x * CV_SCALE;
        lds[(4 * c4 + 1) * 256 + r] = v.y * CV_SCALE;
        lds[(4 * c4 + 2) * 256 + r] = v.z * CV_SCALE;
        lds[(4 * c4 + 3) * 256 + r] = v.w * CV_SCALE;
    }
    __syncthreads();

    // ---- vector part: 136 triu dot pairs, rolled ----
    #pragma clang loop unroll(disable)
    for (int i = 0; i < C1; ++i) {
        const float vi0 = lds[(3 * i + 0) * 256 + tid];
        const float vi1 = lds[(3 * i + 1) * 256 + tid];
        const float vi2 = lds[(3 * i + 2) * 256 + tid];
        const f2* wrow = Wv + i * 8;
        #pragma unroll 2
        for (int q = i >> 1; q < 8; ++q) {
            // v_{2q} components at rows 6q..6q+2, v_{2q+1} at 6q+3..6q+5
            f2 vj0 = f2{lds[(6 * q + 0) * 256 + tid], lds[(6 * q + 3) * 256 + tid]};
            f2 vj1 = f2{lds[(6 * q + 1) * 256 + tid], lds[(6 * q + 4) * 256 + tid]};
            f2 vj2 = f2{lds[(6 * q + 2) * 256 + tid], lds[(6 * q + 5) * 256 + tid]};
            f2 f = vj0 * f2{vi0, vi0};
            f = __builtin_elementwise_fma(vj1, f2{vi1, vi1}, f);
            f = __builtin_elementwise_fma(vj2, f2{vi2, vi2}, f);
            f2 p = __builtin_elementwise_max(f, (f2)0.f);
            f2 m = __builtin_elementwise_min(f, (f2)0.f);
            f2 e; e.x = __builtin_amdgcn_exp2f(m.x);
                  e.y = __builtin_amdgcn_exp2f(m.y);
            f2 w = wrow[q];
            accA = __builtin_elementwise_fma(w, p, accA);
            accB = __builtin_elementwise_fma(w, e, accB);
        }
    }

    const float A1 = accA.x + accA.y;
    const float A2 = accB.x + accB.y;
    const float l2 = fmaf((float)SELU_SCALE, A1,
                          (float)(SELU_SCALE * SELU_ALPHA * LOG2E) * A2);
    const int n = base + tid;
    if (n < N) ex_out[n] = __builtin_amdgcn_exp2f(l2);
}

#define P2T 640   // 32 nodes x 20 float4-channel-groups

__global__ __launch_bounds__(P2T) void pass2_pool(
    const float* __restrict__ nf, const float* __restrict__ ex,
    const int* __restrict__ bounds, float* __restrict__ out)
{
    __shared__ float4 red4[P2T];
    __shared__ float  zred[P2T];
    const int g = blockIdx.x;
    const int tid = threadIdx.x;
    const int start = bounds[g];
    const int end   = bounds[g + 1];

    const int no = tid / 20;      // 0..31
    const int c4 = tid % 20;
    const float4* nf4 = (const float4*)nf;

    float4 a0 = make_float4(0.f, 0.f, 0.f, 0.f), a1 = a0;
    float  z0 = 0.f, z1 = 0.f;
    int n = start + no;
    for (; n + 32 < end; n += 64) {
        float  w0 = ex[n];
        float4 v0 = nf4[(size_t)n * 20 + c4];
        float  w1 = ex[n + 32];
        float4 v1 = nf4[(size_t)(n + 32) * 20 + c4];
        a0.x = fmaf(v0.x, w0, a0.x); a0.y = fmaf(v0.y, w0, a0.y);
        a0.z = fmaf(v0.z, w0, a0.z); a0.w = fmaf(v0.w, w0, a0.w);
        z0 += w0;
        a1.x = fmaf(v1.x, w1, a1.x); a1.y = fmaf(v1.y, w1, a1.y);
        a1.z = fmaf(v1.z, w1, a1.z); a1.w = fmaf(v1.w, w1, a1.w);
        z1 += w1;
    }
    if (n < end) {
        float  w0 = ex[n];
        float4 v0 = nf4[(size_t)n * 20 + c4];
        a0.x = fmaf(v0.x, w0, a0.x); a0.y = fmaf(v0.y, w0, a0.y);
        a0.z = fmaf(v0.z, w0, a0.z); a0.w = fmaf(v0.w, w0, a0.w);
        z0 += w0;
    }
    a0.x += a1.x; a0.y += a1.y; a0.z += a1.z; a0.w += a1.w;
    z0 += z1;

    red4[tid] = a0;
    zred[tid] = z0;
    __syncthreads();
    #pragma unroll
    for (int s = 16; s > 0; s >>= 1) {
        if (no < s) {
            float4 o = red4[tid + s * 20];
            red4[tid].x += o.x; red4[tid].y += o.y;
            red4[tid].z += o.z; red4[tid].w += o.w;
            zred[tid] += zred[tid + s * 20];
        }
        __syncthreads();
    }
    if (tid < 20) {
        float z = zred[tid];
        float inv_z = (z > 0.0f) ? (1.0f / z) : 0.0f;
        float4 r = red4[tid];
        r.x *= inv_z; r.y *= inv_z; r.z *= inv_z; r.w *= inv_z;
        ((float4*)(out + (size_t)g * NODE_F))[tid] = r;
    }
}

extern "C" void kernel_launch(void* const* d_in, const int* in_sizes, int n_in,
                              void* d_out, int out_size, void* d_ws, size_t ws_size,
                              hipStream_t stream) {
    const float* nf = (const float*)d_in[0];   // (N, 80) f32
    const int*   bi = (const int*)d_in[1];     // (N,) i32 sorted
    // d_in[2] = num_graphs (static 1024)
    const float* W  = (const float*)d_in[3];   // (664,) f32
    float* out = (float*)d_out;

    const int N = in_sizes[0] / NODE_F;
    float* ws     = (float*)d_ws;
    float* ex     = ws + WS_OFF_EX;            // N floats
    int*   bounds = (int*)(ws + WS_OFF_EX + N);

    hipLaunchKernelGGL(prep_kernel, dim3(7), dim3(256), 0, stream, bi, W, ws, bounds, N);
    hipLaunchKernelGGL(pass1_logits, dim3((N + 255) / 256), dim3(256), 0, stream,
                       nf, ws, ex, N);
    hipLaunchKernelGGL(pass2_pool, dim3(NG_CONST), dim3(P2T), 0, stream,
                       nf, ex, bounds, out);
}

// Round 5
// 195.191 us; speedup vs baseline: 1.1321x; 1.1321x over previous
//
#include <hip/hip_runtime.h>

// GlobalAttentionPooling: tensor_square_0e -> selu -> @W -> segment softmax -> weighted segment sum
// N nodes, 80 f32 ft (32 scalar + 16 x 3-vec), NG=1024 graphs (sorted batch_index), F=664.
//
// Math identities (validated rounds 1-4, absmax 3.9e-3):
//   selu const term cancels in softmax; pre-scale s by sqrt(log2e), v by sqrt(log2e/sqrt3)
//   so pair products are f*log2e -> exp2 directly. out_g = (sum nf*ex)/z_g.
//
// Round-5 findings driving this version:
//   - VALUBusy pinned at 41% across 4 structurally different pass1s; L3-resident replays
//     (FETCH=1.2MB) still took 90us -> not BW-bound, stalled. Suspect: s_load(W) shares
//     lgkmcnt with ds_read, SMEM completes out-of-order -> full lgkmcnt(0) drains in loop.
//   - Fix: W pre-padded into LDS once; hot loop's only memory op = broadcast ds_read_b64.
//   - Structural: single fused kernel (block owns 320 contiguous nodes; ex/bi in LDS;
//     phase2 re-reads own nf slice from L2; per-graph-run atomic flush into global S/z),
//     eliminating the separate pooling pass (~130us of round-4 total).

typedef float f2 __attribute__((ext_vector_type(2)));

#define C0 32
#define C1 16
#define NODE_F 80
#define NG_CONST 1024
#define NPB 320                 // nodes per block (16 groups x 20 float4 columns)

#define SELU_SCALE 1.0507009873554804934193349852946
#define SELU_ALPHA 1.6732632423543772848170429916717
#define LOG2E      1.4426950408889634073599246810019

#define CS_SCALE 1.2011224087864498f    // sqrt(log2e)
#define CV_SCALE 0.91271231102878545f   // sqrt(log2e/sqrt(3))

// ws float layout:
//   [0, 81920)        S accum: [1024 graphs][80 ch]
//   [81920, 82944)    z accum: [1024]
//   [82944, 84224)    Wpad: 512 f2 scalar-part rows (32x16) then 128 f2 vec-part rows (16x8)
#define WS_S 0
#define WS_Z 81920
#define WS_W 82944

__device__ __forceinline__ int ks_idx(int i, int j) { return i * C0 - (i * (i - 1)) / 2 + (j - i); }
__device__ __forceinline__ int kv_idx(int i, int j) { return 528 + i * C1 - (i * (i - 1)) / 2 + (j - i); }

// zero the accumulators + build padded W tables
__global__ __launch_bounds__(256) void prep_kernel(
    const float* __restrict__ W, float* __restrict__ ws)
{
    const int t = blockIdx.x * blockDim.x + threadIdx.x;
    if (t < 82944) {
        ws[t] = 0.0f;                       // S and z
    } else {
        int u = t - 82944;
        if (u < 512) {                      // Ws: i in [0,32), q in [0,16)
            int i = u >> 4, q = u & 15;
            int j0 = 2 * q, j1 = 2 * q + 1;
            ws[WS_W + 2 * u]     = (j0 >= i) ? W[ks_idx(i, j0)] : 0.0f;
            ws[WS_W + 2 * u + 1] = (j1 >= i) ? W[ks_idx(i, j1)] : 0.0f;
        } else if (u < 640) {               // Wv: i in [0,16), q in [0,8)
            int v = u - 512;
            int i = v >> 3, q = v & 7;
            int j0 = 2 * q, j1 = 2 * q + 1;
            ws[WS_W + 1024 + 2 * v]     = (j0 >= i) ? W[kv_idx(i, j0)] : 0.0f;
            ws[WS_W + 1024 + 2 * v + 1] = (j1 >= i) ? W[kv_idx(i, j1)] : 0.0f;
        }
    }
}

__global__ __launch_bounds__(NPB, 2) void main_kernel(
    const float* __restrict__ nf, const int* __restrict__ bi,
    const float* __restrict__ ws, float* __restrict__ S,
    float* __restrict__ z, int N)
{
    __shared__ __align__(16) float Wlds[1280];
    __shared__ float exl[NPB];
    __shared__ int   bil[NPB];

    const int tid  = threadIdx.x;
    const int base = blockIdx.x * NPB;
    const float4* g4 = (const float4*)nf;

    #pragma unroll
    for (int u = tid; u < 1280; u += NPB) Wlds[u] = ws[WS_W + u];

    const int  n     = base + tid;
    const bool valid = (n < N);
    const int  nn    = valid ? n : (N - 1);
    bil[tid] = bi[nn];
    __syncthreads();                        // Wlds ready

    // ---- phase 1: per-thread row (registers), fully unrolled triangle, DS-only W ----
    float4 row4[20];
    #pragma unroll
    for (int q = 0; q < 20; ++q) row4[q] = g4[(size_t)nn * 20 + q];
    const float* row = (const float*)row4;

    const f2* WsL = (const f2*)Wlds;          // 512 f2
    const f2* WvL = (const f2*)(Wlds + 1024); // 128 f2

    f2 accA[2], accB[2];
    accA[0] = (f2)0.f; accA[1] = (f2)0.f; accB[0] = (f2)0.f; accB[1] = (f2)0.f;

    {   // scalar part: 528 triu pairs as j-pair f2 (272 f2-iters)
        f2 s2[C0 / 2];
        #pragma unroll
        for (int q = 0; q < C0 / 2; ++q)
            s2[q] = f2{row[2 * q], row[2 * q + 1]} * CS_SCALE;
        #pragma unroll
        for (int i = 0; i < C0; ++i) {
            const float si = (i & 1) ? s2[i >> 1].y : s2[i >> 1].x;
            const f2 si2 = f2{si, si};
            #pragma unroll
            for (int q = i >> 1; q < C0 / 2; ++q) {
                f2 f = si2 * s2[q];
                f2 p = __builtin_elementwise_max(f, (f2)0.f);
                f2 m = __builtin_elementwise_min(f, (f2)0.f);
                f2 e; e.x = __builtin_amdgcn_exp2f(m.x);
                      e.y = __builtin_amdgcn_exp2f(m.y);
                f2 w = WsL[i * 16 + q];             // broadcast ds_read_b64, pad slots = 0
                accA[q & 1] = __builtin_elementwise_fma(w, p, accA[q & 1]);
                accB[q & 1] = __builtin_elementwise_fma(w, e, accB[q & 1]);
            }
        }
    }
    {   // vector part: 136 triu dot pairs as j-pair f2 (72 f2-iters)
        f2 vp[C1 / 2][3];
        #pragma unroll
        for (int q = 0; q < C1 / 2; ++q) {
            #pragma unroll
            for (int c = 0; c < 3; ++c)
                vp[q][c] = f2{row[C0 + 6 * q + c], row[C0 + 6 * q + 3 + c]} * CV_SCALE;
        }
        #pragma unroll
        for (int i = 0; i < C1; ++i) {
            const int iq = i >> 1;
            const float vi0 = (i & 1) ? vp[iq][0].y : vp[iq][0].x;
            const float vi1 = (i & 1) ? vp[iq][1].y : vp[iq][1].x;
            const float vi2 = (i & 1) ? vp[iq][2].y : vp[iq][2].x;
            #pragma unroll
            for (int q = i >> 1; q < C1 / 2; ++q) {
                f2 f = vp[q][0] * f2{vi0, vi0};
                f = __builtin_elementwise_fma(vp[q][1], f2{vi1, vi1}, f);
                f = __builtin_elementwise_fma(vp[q][2], f2{vi2, vi2}, f);
                f2 p = __builtin_elementwise_max(f, (f2)0.f);
                f2 m = __builtin_elementwise_min(f, (f2)0.f);
                f2 e; e.x = __builtin_amdgcn_exp2f(m.x);
                      e.y = __builtin_amdgcn_exp2f(m.y);
                f2 w = WvL[i * 8 + q];
                accA[q & 1] = __builtin_elementwise_fma(w, p, accA[q & 1]);
                accB[q & 1] = __builtin_elementwise_fma(w, e, accB[q & 1]);
            }
        }
    }

    const float A1 = accA[0].x + accA[0].y + accA[1].x + accA[1].y;
    const float A2 = accB[0].x + accB[0].y + accB[1].x + accB[1].y;
    const float l2 = fmaf((float)SELU_SCALE, A1,
                          (float)(SELU_SCALE * SELU_ALPHA * LOG2E) * A2);
    exl[tid] = valid ? __builtin_amdgcn_exp2f(l2) : 0.0f;
    __syncthreads();

    // ---- phase 2: thread (no, c4) sums 20 contiguous nodes' channel-group, flush per graph run ----
    const int no = tid / 20;       // 0..15
    const int c4 = tid % 20;
    int cg = bil[no * 20];
    float4 acc = make_float4(0.f, 0.f, 0.f, 0.f);
    float  zacc = 0.0f;

    #pragma unroll
    for (int k = 0; k < 20; ++k) {
        const int nl = no * 20 + k;
        const int g2 = bil[nl];
        if (g2 != cg) {
            unsafeAtomicAdd(&S[cg * NODE_F + c4 * 4 + 0], acc.x);
            unsafeAtomicAdd(&S[cg * NODE_F + c4 * 4 + 1], acc.y);
            unsafeAtomicAdd(&S[cg * NODE_F + c4 * 4 + 2], acc.z);
            unsafeAtomicAdd(&S[cg * NODE_F + c4 * 4 + 3], acc.w);
            if (c4 == 0) unsafeAtomicAdd(&z[cg], zacc);
            acc = make_float4(0.f, 0.f, 0.f, 0.f); zacc = 0.0f; cg = g2;
        }
        int idx = base + nl; if (idx > N - 1) idx = N - 1;   // pad nodes have w=0
        const float  w = exl[nl];
        const float4 v = g4[(size_t)idx * 20 + c4];
        acc.x = fmaf(v.x, w, acc.x); acc.y = fmaf(v.y, w, acc.y);
        acc.z = fmaf(v.z, w, acc.z); acc.w = fmaf(v.w, w, acc.w);
        zacc += w;
    }
    unsafeAtomicAdd(&S[cg * NODE_F + c4 * 4 + 0], acc.x);
    unsafeAtomicAdd(&S[cg * NODE_F + c4 * 4 + 1], acc.y);
    unsafeAtomicAdd(&S[cg * NODE_F + c4 * 4 + 2], acc.z);
    unsafeAtomicAdd(&S[cg * NODE_F + c4 * 4 + 3], acc.w);
    if (c4 == 0) unsafeAtomicAdd(&z[cg], zacc);
}

__global__ __launch_bounds__(256) void divide_kernel(
    const float* __restrict__ S, const float* __restrict__ z,
    float* __restrict__ out)
{
    const int t = blockIdx.x * blockDim.x + threadIdx.x;
    if (t >= NG_CONST * NODE_F) return;
    const float zz = z[t / NODE_F];
    out[t] = (zz > 0.0f) ? (S[t] / zz) : 0.0f;
}

extern "C" void kernel_launch(void* const* d_in, const int* in_sizes, int n_in,
                              void* d_out, int out_size, void* d_ws, size_t ws_size,
                              hipStream_t stream) {
    const float* nf = (const float*)d_in[0];   // (N, 80) f32
    const int*   bi = (const int*)d_in[1];     // (N,) i32 sorted
    // d_in[2] = num_graphs (static 1024)
    const float* W  = (const float*)d_in[3];   // (664,) f32
    float* out = (float*)d_out;

    const int N = in_sizes[0] / NODE_F;
    float* ws = (float*)d_ws;
    float* S  = ws + WS_S;
    float* z  = ws + WS_Z;

    hipLaunchKernelGGL(prep_kernel, dim3(332), dim3(256), 0, stream, W, ws);
    hipLaunchKernelGGL(main_kernel, dim3((N + NPB - 1) / NPB), dim3(NPB), 0, stream,
                       nf, bi, ws, S, z, N);
    hipLaunchKernelGGL(divide_kernel, dim3((NG_CONST * NODE_F + 255) / 256), dim3(256),
                       0, stream, S, z, out);
}